// Round 1
// baseline (40.005 us; speedup 1.0000x reference)
//
#include <hip/hip_runtime.h>
#include <hip/hip_bf16.h>

// Problem constants (fixed by setup_inputs):
//   N = 16384 rows, D_TS = 1022 time-series cols, D = 1024 total cols, C = 2
//   GAMMA = 0.1
// Reference:
//   x = concat(ts, meta0, meta1)                       [N, 1024]
//   S[d] = sum_i x[i,d]; Q[d] = sum_i x[i,d]^2
//   pairwise_sq[i,d] = N*x^2 - 2*x*S[d] + Q[d]
//   feat = exp(-GAMMA * pairwise_sq)
//   out  = feat @ w.T + b                              [N, 2]  (fp32)
//
// Workspace layout (needs 256*1024*2 + 2048 floats ≈ 2.06 MB):
//   psum [256][1024], psq [256][1024], colS [1024], colQ [1024]

#define NROWS   16384
#define DTS     1022
#define DTOT    1024
#define NCHUNK  256          // row chunks for the deterministic 2-level reduce
#define RPC     (NROWS / NCHUNK)   // 64 rows per chunk
#define GAMMA_F 0.1f

// ---------------------------------------------------------------------------
// K1: per-chunk column sums / sq-sums. grid = (2 col-tiles, NCHUNK), 256 thr.
// Each thread owns 2 adjacent columns (float2 loads; row stride 1022 floats
// keeps every even-column element 8B-aligned) and loops 64 rows.
// ---------------------------------------------------------------------------
__global__ __launch_bounds__(256) void colsum_partial(
    const float* __restrict__ ts, const float* __restrict__ m0,
    const float* __restrict__ m1, float* __restrict__ psum,
    float* __restrict__ psq) {
  const int tile  = blockIdx.x;              // 0..1
  const int chunk = blockIdx.y;              // 0..NCHUNK-1
  const int d     = tile * 512 + threadIdx.x * 2;  // even, 0..1022
  const int r0    = chunk * RPC;

  float s0 = 0.f, s1 = 0.f, q0 = 0.f, q1 = 0.f;
  if (d < DTS) {   // both columns come from ts (d+1 <= 1021)
    const float* p = ts + (size_t)r0 * DTS + d;
#pragma unroll 8
    for (int r = 0; r < RPC; ++r) {
      float2 v = *reinterpret_cast<const float2*>(p);
      s0 += v.x; s1 += v.y;
      q0 += v.x * v.x; q1 += v.y * v.y;
      p += DTS;
    }
  } else {         // d == 1022: the two metadata columns
#pragma unroll 8
    for (int r = 0; r < RPC; ++r) {
      float a = m0[r0 + r], b = m1[r0 + r];
      s0 += a; s1 += b;
      q0 += a * a; q1 += b * b;
    }
  }
  const int o = chunk * DTOT + d;
  *reinterpret_cast<float2*>(psum + o) = make_float2(s0, s1);
  *reinterpret_cast<float2*>(psq + o)  = make_float2(q0, q1);
}

// ---------------------------------------------------------------------------
// K2: reduce NCHUNK partials per column. grid = 4 x 256 threads (one per col).
// ---------------------------------------------------------------------------
__global__ __launch_bounds__(256) void colsum_final(
    const float* __restrict__ psum, const float* __restrict__ psq,
    float* __restrict__ colS, float* __restrict__ colQ) {
  const int d = blockIdx.x * 256 + threadIdx.x;  // 0..1023
  float s = 0.f, q = 0.f;
#pragma unroll 16
  for (int c = 0; c < NCHUNK; ++c) {
    s += psum[c * DTOT + d];
    q += psq[c * DTOT + d];
  }
  colS[d] = s;
  colQ[d] = q;
}

// ---------------------------------------------------------------------------
// K3: fused feat + GEMV. One wave per row; 4 waves/block; grid = N/4 blocks.
// Stages w0, w1, 2*gamma*S, -gamma*Q in LDS (16 KB). Per lane: 8 float2
// loads covering the 1024 columns; exp + 2-way dot accumulate; wave-reduce.
// ---------------------------------------------------------------------------
__global__ __launch_bounds__(256) void svm_logits(
    const float* __restrict__ ts, const float* __restrict__ m0,
    const float* __restrict__ m1, const float* __restrict__ w,
    const float* __restrict__ b, const float* __restrict__ colS,
    const float* __restrict__ colQ, float* __restrict__ out) {
  __shared__ float sW0[DTOT], sW1[DTOT], sC1[DTOT], sC0[DTOT];
  const int tid = threadIdx.x;
  for (int k = tid; k < DTOT; k += 256) {
    sW0[k] = w[k];
    sW1[k] = w[DTOT + k];
    sC1[k] = 2.0f * GAMMA_F * colS[k];
    sC0[k] = -GAMMA_F * colQ[k];
  }
  __syncthreads();

  const int wave = tid >> 6, lane = tid & 63;
  const int i = blockIdx.x * 4 + wave;           // row index, < 16384
  const float c2 = -GAMMA_F * (float)NROWS;      // -gamma*N

  const float* row = ts + (size_t)i * DTS;
  float acc0 = 0.f, acc1 = 0.f;
#pragma unroll
  for (int k = 0; k < 8; ++k) {
    const int d = k * 128 + lane * 2;            // even, 0..1022
    float x0, x1;
    if (d < DTS) {
      float2 v = *reinterpret_cast<const float2*>(row + d);
      x0 = v.x; x1 = v.y;
    } else {                                     // d == 1022 -> meta columns
      x0 = m0[i]; x1 = m1[i];
    }
    const float p0 = (c2 * x0 + sC1[d]) * x0 + sC0[d];
    const float p1 = (c2 * x1 + sC1[d + 1]) * x1 + sC0[d + 1];
    const float f0 = __expf(p0);
    const float f1 = __expf(p1);
    acc0 += f0 * sW0[d] + f1 * sW0[d + 1];
    acc1 += f0 * sW1[d] + f1 * sW1[d + 1];
  }

  // 64-lane butterfly reduction
#pragma unroll
  for (int off = 32; off; off >>= 1) {
    acc0 += __shfl_down(acc0, off);
    acc1 += __shfl_down(acc1, off);
  }
  if (lane == 0) {
    out[i * 2 + 0] = acc0 + b[0];
    out[i * 2 + 1] = acc1 + b[1];
  }
}

extern "C" void kernel_launch(void* const* d_in, const int* in_sizes, int n_in,
                              void* d_out, int out_size, void* d_ws,
                              size_t ws_size, hipStream_t stream) {
  const float* ts = (const float*)d_in[0];   // [16384, 1022]
  const float* m0 = (const float*)d_in[1];   // [16384]
  const float* m1 = (const float*)d_in[2];   // [16384]
  const float* w  = (const float*)d_in[3];   // [2, 1024]
  const float* b  = (const float*)d_in[4];   // [2]
  float* out = (float*)d_out;                // [16384, 2]

  float* psum = (float*)d_ws;                // [NCHUNK][1024]
  float* psq  = psum + NCHUNK * DTOT;        // [NCHUNK][1024]
  float* colS = psq + NCHUNK * DTOT;         // [1024]
  float* colQ = colS + DTOT;                 // [1024]

  colsum_partial<<<dim3(2, NCHUNK), 256, 0, stream>>>(ts, m0, m1, psum, psq);
  colsum_final<<<dim3(4), 256, 0, stream>>>(psum, psq, colS, colQ);
  svm_logits<<<dim3(NROWS / 4), 256, 0, stream>>>(ts, m0, m1, w, b, colS,
                                                  colQ, out);
}